// Round 3
// baseline (1292.496 us; speedup 1.0000x reference)
//
#include <hip/hip_runtime.h>
#include <hip/hip_fp16.h>

// RNN_16492674416646: h_t = tanh(x_t W_ih^T + b_ih + b_hh + h_{t-1} W_hh^T),
// out_t = h_t W_out^T + b_out. T=2048, B=128, IN=2, H=200, OUT=1, fp32.
//
// R16: back to R13's 16-wave structure (best measured: 1114 us; 4 waves/SIMD
// is the only latency hiding a barrier-locked recurrence gets -- R15's
// 8-wave variant proved throughput cuts that cost occupancy lose). All
// changes attack the SYNCHRONIZED per-step critical path:
//  - t-loop unrolled x8 (RS=8, T%8==0): ring addresses = one invariant
//    vaddr + static 16-bit offset immediates; no per-step slot VALU.
//  - MFMA chains 2+2+2+1 (dep depth 4 -> 2).
//  - drains moved OFF the tile-waves: waves 13/14 (idle in R13) drain one
//    slot per step during compute into an LDS out-buffer; wave 15 flushes
//    64 outputs to HBM every 64 steps (vmcnt barrier-drain amortized).
//    Removes R13's periodic drain phase + extra barrier entirely.
//  - xs read as b128 every 4 steps (static reg picks) instead of 2xb32/step.
//  - drain reads: 2x ds_read_b64 (4 cols/lane) instead of 14 scalar b16.
// Precision identical to R13 (same MFMA layout, fp16 W, split-fp16 h):
// absmax 0.0078 < 0.029.

typedef short s8v __attribute__((ext_vector_type(8)));   // 8 x fp16 bits
typedef short s4v __attribute__((ext_vector_type(4)));   // 4 x fp16 bits
typedef float f4v __attribute__((ext_vector_type(4)));

static constexpr int T = 2048;
static constexpr int B = 128;
static constexpr int H = 200;
static constexpr int NTHR = 1024;  // 16 waves
static constexpr int NT  = 13;     // n-tiles of 16 (208 >= 200)
static constexpr int KT  = 7;      // k-tiles of 32 (224 padded)
static constexpr int HP  = 224;    // padded H
static constexpr int RS  = 8;      // ring slots; T % RS == 0

__device__ __forceinline__ unsigned short f2h(float f) {
    const __half h = __float2half_rn(f);
    return *(const unsigned short*)&h;
}
__device__ __forceinline__ float h2f(unsigned short u) {
    const __half h = *(const __half*)&u;
    return __half2float(h);
}

__global__ __attribute__((amdgpu_flat_work_group_size(NTHR, NTHR),
                          amdgpu_waves_per_eu(4, 4)))
void rnn_fused(const float* __restrict__ x,     // [T,B,2]
               const float* __restrict__ W_ih,  // [H,2]
               const float* __restrict__ W_hh,  // [H,H]
               const float* __restrict__ b_ih,  // [H]
               const float* __restrict__ b_hh,  // [H]
               const float* __restrict__ W_out, // [1,H]
               const float* __restrict__ b_out, // [1]
               float* __restrict__ out)         // [T,B]
{
    const int b    = blockIdx.x;
    const int tid  = threadIdx.x;
    const int w    = tid >> 6;       // wave id 0..15
    const int lane = tid & 63;
    const int m    = lane & 15;      // A-row sel / B-col / D-col
    const int q    = lane >> 4;      // k-quad

    const bool hasT = (w < NT);      // waves 13,14: drain; wave 15: flush
    const int  nA   = 16 * w + m;
    const bool colv = hasT && (nA < H);

    // ring[slot][hi=0/lo=1][col]; lo at +448 B = 64 mod 128 -> per-kt chunk
    // hi/lo hit complementary bank halves: conflict-free (R11-R13: 0).
    __shared__ __align__(16) unsigned short ring[RS][2][HP];  // 7 KiB
    __shared__ __align__(16) float xs[2 * T];                 // 16 KiB
    __shared__ __align__(16) float obuf[128];                 // 2x64 out ring

    for (int i = tid; i < RS * 2 * HP; i += NTHR) (&ring[0][0][0])[i] = 0;
    for (int idx = tid; idx < T; idx += NTHR) {
        const float2 v = *(const float2*)(x + (size_t)idx * (B * 2) + 2 * b);
        xs[2 * idx] = v.x; xs[2 * idx + 1] = v.y;
    }

    // --- loop-invariant B-fragment (fp16): B[k][n]=W_hh[n][k], n=nA ---
    s8v BA[KT];
#pragma unroll
    for (int kt = 0; kt < KT; ++kt) {
        s8v ba{};
        if (colv) {
#pragma unroll
            for (int j = 0; j < 8; ++j) {
                const int ks = 32 * kt + 8 * q + j;
                ba[j] = (short)((ks < H) ? f2h(W_hh[nA * H + ks])
                                         : (unsigned short)0);
            }
        }
        BA[kt] = ba;
    }

    // --- epilogue constants (q==0 lanes of tile waves own col nA) ---
    const float wxA0 = colv ? W_ih[nA * 2]     : 0.f;
    const float wxA1 = colv ? W_ih[nA * 2 + 1] : 0.f;
    const float bA   = colv ? (b_ih[nA] + b_hh[nA]) : 0.f;

    // --- head constants: lane covers cols 4*lane..4*lane+3 ---
    const int c4 = 4 * lane;
    f4v wo = {0.f, 0.f, 0.f, 0.f};
    if (c4 + 3 < H) wo = *(const f4v*)(W_out + c4);   // lanes 0..49
    const float bo = b_out[0];

    __syncthreads();

    // loop-invariant LDS addresses (slot offsets fold into ds imm):
    const unsigned short* aptr = &ring[0][(m == 1) ? 1 : 0][8 * q];
    float* const op = out + b;

    // drain slot -> obuf[tout & 127]. 2x ds_read_b64, 4 cols/lane.
    auto drain = [&](int slot, int tout) {
        float v = 0.f;
        if (lane < 56) {   // cols 0..223; pads (200..223) are 0, wo=0 there
            const s4v hv = *(const s4v*)(&ring[slot][0][0] + c4);
            const s4v lv = *(const s4v*)(&ring[slot][1][0] + c4);
            v = (h2f((unsigned short)hv[0]) + h2f((unsigned short)lv[0])) * wo[0]
              + (h2f((unsigned short)hv[1]) + h2f((unsigned short)lv[1])) * wo[1]
              + (h2f((unsigned short)hv[2]) + h2f((unsigned short)lv[2])) * wo[2]
              + (h2f((unsigned short)hv[3]) + h2f((unsigned short)lv[3])) * wo[3];
        }
#pragma unroll
        for (int off = 32; off > 0; off >>= 1)
            v += __shfl_down(v, off, 64);
        if (lane == 0) obuf[tout & 127] = v + bo;
    };

    for (int t8 = 0; t8 < T / RS; ++t8) {
        f4v xv0 = {0.f, 0.f, 0.f, 0.f};
        f4v xv1 = {0.f, 0.f, 0.f, 0.f};
#pragma unroll
        for (int rp = 0; rp < RS; ++rp) {
            const int sr = (rp + RS - 1) & (RS - 1);   // static
            if (hasT) {
                if (rp == 0) {          // x for steps rp=0..3
                    xv0 = *(const f4v*)(xs + 16 * t8);
                    xv1 = *(const f4v*)(xs + 16 * t8 + 4);
                } else if (rp == 4) {   // x for steps rp=4..7
                    xv0 = *(const f4v*)(xs + 16 * t8 + 8);
                    xv1 = *(const f4v*)(xs + 16 * t8 + 12);
                }
                const int r2 = rp & 3;  // static register picks
                const float x0 = (r2 == 0) ? xv0[0] : (r2 == 1) ? xv0[2]
                               : (r2 == 2) ? xv1[0] : xv1[2];
                const float x1 = (r2 == 0) ? xv0[1] : (r2 == 1) ? xv0[3]
                               : (r2 == 2) ? xv1[1] : xv1[3];
                const float xterm = fmaf(x0, wxA0, fmaf(x1, wxA1, bA));

                // A: row 0 <- h_hi, row 1 <- h_lo (one instr covers both);
                // vaddr invariant, slot/kt in the offset immediate.
                const s8v A0 = *(const s8v*)(aptr + sr * 448 +   0);
                const s8v A1 = *(const s8v*)(aptr + sr * 448 +  32);
                const s8v A2 = *(const s8v*)(aptr + sr * 448 +  64);
                const s8v A3 = *(const s8v*)(aptr + sr * 448 +  96);
                const s8v A4 = *(const s8v*)(aptr + sr * 448 + 128);
                const s8v A5 = *(const s8v*)(aptr + sr * 448 + 160);
                const s8v A6 = *(const s8v*)(aptr + sr * 448 + 192);

                // 4 chains, dep depth <= 2
                f4v u0 = {0.f, 0.f, 0.f, 0.f};
                f4v u1 = {0.f, 0.f, 0.f, 0.f};
                f4v u2 = {0.f, 0.f, 0.f, 0.f};
                f4v u3 = {0.f, 0.f, 0.f, 0.f};
                u0 = __builtin_amdgcn_mfma_f32_16x16x32_f16(A0, BA[0], u0, 0, 0, 0);
                u1 = __builtin_amdgcn_mfma_f32_16x16x32_f16(A2, BA[2], u1, 0, 0, 0);
                u2 = __builtin_amdgcn_mfma_f32_16x16x32_f16(A4, BA[4], u2, 0, 0, 0);
                u3 = __builtin_amdgcn_mfma_f32_16x16x32_f16(A6, BA[6], u3, 0, 0, 0);
                u0 = __builtin_amdgcn_mfma_f32_16x16x32_f16(A1, BA[1], u0, 0, 0, 0);
                u1 = __builtin_amdgcn_mfma_f32_16x16x32_f16(A3, BA[3], u1, 0, 0, 0);
                u2 = __builtin_amdgcn_mfma_f32_16x16x32_f16(A5, BA[5], u2, 0, 0, 0);

                if (q == 0 && nA < H) {
                    const float y = ((u0[0] + u0[1]) + (u1[0] + u1[1]))
                                  + ((u2[0] + u2[1]) + (u3[0] + u3[1]));
                    const float pre = y + xterm;
                    const float e   = __expf(2.f * pre);      // tanh
                    const float th  = 1.f - 2.f / (e + 1.f);
                    const unsigned short hi = f2h(th);
                    (&ring[rp][0][0])[nA] = hi;
                    (&ring[rp][1][0])[nA] = f2h(th - h2f(hi));
                }
            } else if (w == 13 || w == 14) {
                // drain slot (rp+1): holds h of step t-7, stable (written 7
                // steps ago, rewritten only at t+1, ordered by barriers).
                // w13: even rp, w14: odd rp -> each slot once per 8 steps.
                if (((rp ^ (w - 13)) & 1) == 0) {
                    if (rp == 7 || t8 > 0) {
                        const int t = 8 * t8 + rp;
                        drain((rp + 1) & 7, t - 7);
                    }
                }
            } else {   // w == 15: flush chunk c = outputs [64c,64c+64) to HBM
                if (rp == 0 && (t8 & 7) == 1 && t8 > 8) {
                    const int c = (t8 >> 3) - 1;
                    const float val = obuf[((c & 1) << 6) | lane];
                    op[(size_t)(64 * c + lane) * B] = val;
                }
            }
            __syncthreads();
        }
    }

    // --- tail: outputs 2041..2047 sit in slots 1..7; then flush chunk 31 ---
    if (w < 7) drain(w + 1, T - 7 + w);
    __syncthreads();
    if (w == 15) {
        const float val = obuf[64 | lane];
        op[(size_t)(1984 + lane) * B] = val;
    }
}

extern "C" void kernel_launch(void* const* d_in, const int* in_sizes, int n_in,
                              void* d_out, int out_size, void* d_ws, size_t ws_size,
                              hipStream_t stream) {
    const float* x     = (const float*)d_in[0];
    const float* W_ih  = (const float*)d_in[1];
    const float* W_hh  = (const float*)d_in[2];
    const float* b_ih  = (const float*)d_in[3];
    const float* b_hh  = (const float*)d_in[4];
    const float* W_out = (const float*)d_in[5];
    const float* b_out = (const float*)d_in[6];
    float* out = (float*)d_out;

    rnn_fused<<<B, NTHR, 0, stream>>>(x, W_ih, W_hh, b_ih, b_hh, W_out, b_out, out);
}

// Round 4
// 1238.683 us; speedup vs baseline: 1.0434x; 1.0434x over previous
//
#include <hip/hip_runtime.h>
#include <hip/hip_fp16.h>

// RNN_16492674416646: h_t = tanh(x_t W_ih^T + b_ih + b_hh + h_{t-1} W_hh^T),
// out_t = h_t W_out^T + b_out. T=2048, B=128, IN=2, H=200, OUT=1, fp32.
//
// R17 = R13's exact structure (16 waves, 13 tile-waves, batched drain,
// 1 barrier/step -- best measured 1114 us) with the MFMA switched from
// f16 K=32 to i8 K=64: A-reads drop 7 -> 4 per wave (91 -> 52 ds_read_b128
// per step). Model: R13 step (1305 cyc) ~= LDS-pipe instruction occupancy
// (R14 proved no broadcast discount; R15 proved occupancy must stay 4/SIMD;
// R16 proved no per-step straggler waves).
//
// Numerics (all int8 dual-split, errors BELOW the old fp16-W scheme):
//   h  = hq/127 + hr/32000            (|err| <= 1.6e-5)
//   W  = Wq*gam + Wr*gam/252          (per-COLUMN gam = colmax/127, err ~5e-6)
//   y  = (1/127)(gam*QQ + del*QR) + (1/32000)(gam*RQ + del*RR)
// where QQ,RQ come from MFMA(B=Wq) rows 0,1 and QR,RR from MFMA(B=Wr):
// A row 0 = hq, row 1 = hr, rows 2..15 dup row 0 (ignored). i32 accum exact
// (max 224*127*127 = 3.6e6). All four cross terms kept (RR is free).
//
// Ring slot layout (640 B): hq[256] | pad 64 | hr[256] | pad 64.
// A-read banks: m=0 lanes hit banks 0..15, m=1 (+320 B) banks 16..31,
// m>=2 duplicate m=0 (same-addr broadcast): conflict-free.
// Ring write: one ds_write_b16 per lane (16 lanes), byte-paired via DPP
// quad_perm(1,0,3,2): even lanes write (hq_m,hq_m+1), odd (hr_m-1,hr_m);
// 16 lanes over 8 banks = 2/bank (free).

typedef int   i4v __attribute__((ext_vector_type(4)));
typedef float f4v __attribute__((ext_vector_type(4)));

static constexpr int T = 2048;
static constexpr int B = 128;
static constexpr int H = 200;
static constexpr int NTHR = 1024;  // 16 waves
static constexpr int NT  = 13;     // n-tiles of 16 (208 >= 200)
static constexpr int KT  = 4;      // k-tiles of 64 (256 padded)
static constexpr int RS  = 8;      // ring slots; T % RS == 0
static constexpr int SLOT = 640;   // bytes per slot
static constexpr int HROFF = 320;  // hr row offset within slot

static constexpr float HA  = 1.f / 127.f;    // h hi scale
static constexpr float HB  = 1.f / 32000.f;  // h lo scale (126 max, no clamp)

__global__ __attribute__((amdgpu_flat_work_group_size(NTHR, NTHR),
                          amdgpu_waves_per_eu(4, 4)))
void rnn_fused(const float* __restrict__ x,     // [T,B,2]
               const float* __restrict__ W_ih,  // [H,2]
               const float* __restrict__ W_hh,  // [H,H]
               const float* __restrict__ b_ih,  // [H]
               const float* __restrict__ b_hh,  // [H]
               const float* __restrict__ W_out, // [1,H]
               const float* __restrict__ b_out, // [1]
               float* __restrict__ out)         // [T,B]
{
    const int b    = blockIdx.x;
    const int tid  = threadIdx.x;
    const int w    = tid >> 6;       // wave id 0..15
    const int lane = tid & 63;
    const int m    = lane & 15;      // A-row sel / B-col / D-col
    const int q    = lane >> 4;      // k-quad (16 consecutive k per lane)

    const bool hasT = (w < NT);      // waves 13..15: barriers only
    const int  nA   = 16 * w + m;
    const bool colv = hasT && (nA < H);

    __shared__ __align__(16) char  rbase[RS * SLOT];  // 5 KiB ring
    __shared__ __align__(16) float xs[2 * T];         // 16 KiB

    for (int i = tid; i < RS * SLOT; i += NTHR) rbase[i] = 0;
    for (int idx = tid; idx < T; idx += NTHR) {
        const float2 v = *(const float2*)(x + (size_t)idx * (B * 2) + 2 * b);
        xs[2 * idx] = v.x; xs[2 * idx + 1] = v.y;
    }

    // --- per-column W scale: gam = colmax/127 (lanes of same m share) ---
    float cm = 0.f;
    if (colv) {
#pragma unroll
        for (int kt = 0; kt < KT; ++kt)
#pragma unroll
            for (int j = 0; j < 16; ++j) {
                const int ks = 64 * kt + 16 * q + j;
                if (ks < H) cm = fmaxf(cm, fabsf(W_hh[nA * H + ks]));
            }
    }
    cm = fmaxf(cm, __shfl_xor(cm, 16, 64));
    cm = fmaxf(cm, __shfl_xor(cm, 32, 64));
    const float gam = cm * (1.f / 127.f);
    const float del = gam * (1.f / 252.f);          // Wr max 126, no clamp
    const float ivg = (cm > 0.f) ? (127.f / cm) : 0.f;
    const float ivd = (cm > 0.f) ? (32004.f / cm) : 0.f;   // 1/del

    // --- loop-invariant B-fragments: Wq, Wr (int8, 16 k per lane) ---
    i4v BQ[KT], BR[KT];
#pragma unroll
    for (int kt = 0; kt < KT; ++kt) {
        i4v vq = {0, 0, 0, 0}, vr = {0, 0, 0, 0};
        if (colv) {
#pragma unroll
            for (int j = 0; j < 16; ++j) {
                const int ks = 64 * kt + 16 * q + j;
                const float Wv = (ks < H) ? W_hh[nA * H + ks] : 0.f;
                const float fq = rintf(Wv * ivg);
                const float fr = rintf(fmaf(-fq, gam, Wv) * ivd);
                vq[j >> 2] |= (((int)fq) & 0xFF) << (8 * (j & 3));
                vr[j >> 2] |= (((int)fr) & 0xFF) << (8 * (j & 3));
            }
        }
        BQ[kt] = vq; BR[kt] = vr;
    }

    // --- epilogue constants (q==0 lanes own col nA) ---
    const float a1 = gam * HA, a2 = del * HA;   // * QQ, * QR
    const float a3 = gam * HB, a4 = del * HB;   // * RQ, * RR
    const float wxA0 = colv ? W_ih[nA * 2]     : 0.f;
    const float wxA1 = colv ? W_ih[nA * 2 + 1] : 0.f;
    const float bA   = colv ? (b_ih[nA] + b_hh[nA]) : 0.f;

    // --- head constants: lane covers cols 4*lane..4*lane+3 ---
    const int c4 = 4 * lane;
    f4v wo = {0.f, 0.f, 0.f, 0.f};
    if (c4 + 3 < H) wo = *(const f4v*)(W_out + c4);   // pads stay 0
    const float bo = b_out[0];

    __syncthreads();

    float* const op = out + b;
    const char* const apb = rbase + ((m == 1) ? HROFF : 0) + 16 * q;

    // drain slot -> out[tout]. 2x ds_read_b32 (4 cols/lane) + shfl reduce.
    auto drain = [&](int slot, int tout) {
        const char* sp = rbase + slot * SLOT;
        const int hq4 = *(const int*)(sp + c4);
        const int hr4 = *(const int*)(sp + HROFF + c4);
        float sq = 0.f, sr2 = 0.f;
#pragma unroll
        for (int j = 0; j < 4; ++j) {
            const float qj = (float)((signed char)((hq4 >> (8 * j)) & 0xFF));
            const float rj = (float)((signed char)((hr4 >> (8 * j)) & 0xFF));
            sq  = fmaf(qj, wo[j], sq);
            sr2 = fmaf(rj, wo[j], sr2);
        }
        float v = fmaf(HA, sq, HB * sr2);
#pragma unroll
        for (int off = 32; off > 0; off >>= 1)
            v += __shfl_down(v, off, 64);
        if (lane == 0) op[(size_t)tout * B] = v + bo;
    };

    int rp = 0;                          // t % RS
    for (int t = 0; t < T; ++t) {
        // batched drain every RS steps (R13 structure, waves 0..7)
        if (rp == 0 && t) {
            if (w < RS) drain(w, t - RS + w);
            __syncthreads();
        }
        const int sr = rp ? rp - 1 : RS - 1;
        const int sw = rp;

        if (hasT) {
            const float x0 = xs[2 * t], x1 = xs[2 * t + 1];
            const float xterm = fmaf(x0, wxA0, fmaf(x1, wxA1, bA));

            // A: row0 hq, row1 hr, rows 2..15 dup row0. 4 reads (K=64 each).
            const char* ap = apb + sr * SLOT;
            const i4v A0 = *(const i4v*)(ap);
            const i4v A1 = *(const i4v*)(ap + 64);
            const i4v A2 = *(const i4v*)(ap + 128);
            const i4v A3 = *(const i4v*)(ap + 192);

            // 4 chains (Wq x2, Wr x2), dep depth 2
            const i4v z = {0, 0, 0, 0};
            i4v qa = __builtin_amdgcn_mfma_i32_16x16x64_i8(A0, BQ[0], z, 0, 0, 0);
            i4v ra = __builtin_amdgcn_mfma_i32_16x16x64_i8(A0, BR[0], z, 0, 0, 0);
            i4v qb = __builtin_amdgcn_mfma_i32_16x16x64_i8(A2, BQ[2], z, 0, 0, 0);
            i4v rb = __builtin_amdgcn_mfma_i32_16x16x64_i8(A2, BR[2], z, 0, 0, 0);
            qa = __builtin_amdgcn_mfma_i32_16x16x64_i8(A1, BQ[1], qa, 0, 0, 0);
            ra = __builtin_amdgcn_mfma_i32_16x16x64_i8(A1, BR[1], ra, 0, 0, 0);
            qb = __builtin_amdgcn_mfma_i32_16x16x64_i8(A3, BQ[3], qb, 0, 0, 0);
            rb = __builtin_amdgcn_mfma_i32_16x16x64_i8(A3, BR[3], rb, 0, 0, 0);

            if (q == 0 && nA < H) {
                const float fQQ = (float)(qa[0] + qb[0]);
                const float fRQ = (float)(qa[1] + qb[1]);
                const float fQR = (float)(ra[0] + rb[0]);
                const float fRR = (float)(ra[1] + rb[1]);
                const float y  = fmaf(a1, fQQ, fmaf(a2, fQR,
                                 fmaf(a3, fRQ, a4 * fRR)));
                const float pre = y + xterm;
                const float e   = __expf(2.f * pre);      // tanh, saturating
                const float th  = 1.f - 2.f / (e + 1.f);

                // quantize h -> (hq, hr)
                const float fq = rintf(th * 127.f);
                const float fr = rintf(fmaf(fq, -HA, th) * 32000.f);
                const int iq = ((int)fq) & 0xFF;
                const int ir = ((int)fr) & 0xFF;

                // DPP byte-pair: even lanes write (hq_m,hq_{m+1}) to hq row,
                // odd lanes write (hr_{m-1},hr_m) to hr row. One b16/lane.
                const int nq = __builtin_amdgcn_update_dpp(0, iq, 0xB1, 0xF, 0xF, true);
                const int nr = __builtin_amdgcn_update_dpp(0, ir, 0xB1, 0xF, 0xF, true);
                char* sb = rbase + sw * SLOT;
                const bool ev = ((m & 1) == 0);
                const unsigned short wdat = ev
                    ? (unsigned short)(iq | (nq << 8))
                    : (unsigned short)(nr | (ir << 8));
                char* wadr = ev ? (sb + nA) : (sb + HROFF + nA - 1);
                *(unsigned short*)wadr = wdat;
            }
        }
        __syncthreads();
        if (++rp == RS) rp = 0;
    }

    // --- tail: last RS steps sit in slots 0..7 ---
    if (w < RS) drain(w, T - RS + w);
}

extern "C" void kernel_launch(void* const* d_in, const int* in_sizes, int n_in,
                              void* d_out, int out_size, void* d_ws, size_t ws_size,
                              hipStream_t stream) {
    const float* x     = (const float*)d_in[0];
    const float* W_ih  = (const float*)d_in[1];
    const float* W_hh  = (const float*)d_in[2];
    const float* b_ih  = (const float*)d_in[3];
    const float* b_hh  = (const float*)d_in[4];
    const float* W_out = (const float*)d_in[5];
    const float* b_out = (const float*)d_in[6];
    float* out = (float*)d_out;

    rnn_fused<<<B, NTHR, 0, stream>>>(x, W_ih, W_hh, b_ih, b_hh, W_out, b_out, out);
}

// Round 6
// 1156.360 us; speedup vs baseline: 1.1177x; 1.0712x over previous
//
#include <hip/hip_runtime.h>
#include <hip/hip_fp16.h>

// RNN_16492674416646: h_t = tanh(x_t W_ih^T + b_ih + b_hh + h_{t-1} W_hh^T),
// out_t = h_t W_out^T + b_out. T=2048, B=128, IN=2, H=200, OUT=1, fp32.
//
// R18b = R18 with the dpp_add ctrl made a template constant (compile fix;
// __builtin_amdgcn_update_dpp requires a literal dpp_ctrl).
//
// Model (fits R13-R17): step = LDS-read-queue (every wave's first MFMA
// waits behind the phase-locked burst) + serial tail (MFMA dep + epilogue
// VALU) + barrier. R13 = 91 b128 x 12cy ~ 1100 + 200. R15 cut the queue but
// halved occupancy; R17 cut it but added ~100us of quantize-VALU tail; R16
// put DS-pipe shuffles on a straggler. R18 combines the non-broken parts:
//  - 16 waves (4/SIMD, R13 occupancy): 8 TILE-waves, 8 DRAIN-waves.
//  - tile-waves own {2,2,2,2,1,2,1,1} n-tiles; ONE A-read set (7 b128)
//    shared across both tiles -> 56 reads/step (was 91).
//  - drains spread: one output per phase (9 phases stale, 64-deep ring),
//    VALU-ONLY reduce (DPP xor-butterfly + readlane; zero DS-pipe ops ->
//    no R16 straggle), into LDS obuf; wave 14 (phase-idle at flush steps)
//    stores 64 outputs to HBM once per 64 phases.
//  - ring writes DPP-paired to b32 (13 instrs, was 26); xs read as b64.
// Numerics identical to R13 (fp16 W, split-fp16 h, same MFMA): absmax
// 0.0078 < 0.029. Ring slot 896 B = 0 mod 128 -> R13's hi/lo bank-disjoint
// layout preserved (lo at +448 B).

typedef short s8v __attribute__((ext_vector_type(8)));   // 8 x fp16 bits
typedef short s4v __attribute__((ext_vector_type(4)));   // 4 x fp16 bits
typedef float f4v __attribute__((ext_vector_type(4)));

static constexpr int T = 2048;
static constexpr int B = 128;
static constexpr int H = 200;
static constexpr int NTHR = 1024;  // 16 waves
static constexpr int KT  = 7;      // k-tiles of 32 (224 padded)
static constexpr int HP  = 224;    // padded H
static constexpr int RS  = 64;     // ring slots (64 deep; 56 KiB)

__device__ __forceinline__ unsigned short f2h(float f) {
    const __half h = __float2half_rn(f);
    return *(const unsigned short*)&h;
}
__device__ __forceinline__ float h2f(unsigned short u) {
    const __half h = *(const __half*)&u;
    return __half2float(h);
}
// VALU-only cross-lane add (DPP), no LDS pipe. CTRL must be a literal.
template <int CTRL>
__device__ __forceinline__ float dpp_add(float v) {
    const int i = __builtin_bit_cast(int, v);
    const int p = __builtin_amdgcn_update_dpp(0, i, CTRL, 0xF, 0xF, false);
    return v + __builtin_bit_cast(float, p);
}

__global__ __attribute__((amdgpu_flat_work_group_size(NTHR, NTHR),
                          amdgpu_waves_per_eu(4, 4)))
void rnn_fused(const float* __restrict__ x,     // [T,B,2]
               const float* __restrict__ W_ih,  // [H,2]
               const float* __restrict__ W_hh,  // [H,H]
               const float* __restrict__ b_ih,  // [H]
               const float* __restrict__ b_hh,  // [H]
               const float* __restrict__ W_out, // [1,H]
               const float* __restrict__ b_out, // [1]
               float* __restrict__ out)         // [T,B]
{
    const int b    = blockIdx.x;
    const int tid  = threadIdx.x;
    const int w    = tid >> 6;       // wave id 0..15
    const int lane = tid & 63;
    const int m    = lane & 15;      // A-row sel / B-col / D-col
    const int q    = lane >> 4;      // k-quad

    const bool isTile = (w < 8);
    // tiles/wave {2,2,2,2,1,2,1,1}, starts {0,2,4,6,8,9,11,12}:
    // SIMD (w&3) tile loads = {3,4,3,3} -> balanced.
    const int dfc = (w > 4) + (w > 6);
    const int t0  = 2 * w - dfc;
    const int tn  = (w == 4 || w == 6 || w == 7) ? 1 : 2;
    const int nA0 = 16 * t0 + m;
    const int nA1 = 16 * (t0 + 1) + m;
    const bool cv0 = isTile && (nA0 < H);
    const bool cv1 = isTile && (tn == 2) && (nA1 < H);

    __shared__ __align__(16) unsigned short ring[RS][2][HP];  // 56 KiB
    __shared__ __align__(16) float xs[2 * T];                 // 16 KiB
    __shared__ __align__(16) float obuf[128];                 // out staging

    for (int i = tid; i < RS * 2 * HP; i += NTHR) (&ring[0][0][0])[i] = 0;
    for (int idx = tid; idx < T; idx += NTHR) {
        const float2 v = *(const float2*)(x + (size_t)idx * (B * 2) + 2 * b);
        xs[2 * idx] = v.x; xs[2 * idx + 1] = v.y;
    }

    // --- loop-invariant B-fragments (fp16): B[k][n]=W_hh[n][k] ---
    s8v BA0[KT], BA1[KT];
#pragma unroll
    for (int kt = 0; kt < KT; ++kt) {
        s8v b0{}, b1{};
        if (cv0) {
#pragma unroll
            for (int j = 0; j < 8; ++j) {
                const int ks = 32 * kt + 8 * q + j;
                b0[j] = (short)((ks < H) ? f2h(W_hh[nA0 * H + ks])
                                         : (unsigned short)0);
            }
        }
        if (cv1) {
#pragma unroll
            for (int j = 0; j < 8; ++j) {
                const int ks = 32 * kt + 8 * q + j;
                b1[j] = (short)((ks < H) ? f2h(W_hh[nA1 * H + ks])
                                         : (unsigned short)0);
            }
        }
        BA0[kt] = b0; BA1[kt] = b1;
    }

    // --- epilogue constants (q==0 lanes own cols nA0/nA1; invalid cols
    // get 0 -> th = tanh(0) = 0 -> pads stay exactly 0) ---
    const float wx00 = cv0 ? W_ih[nA0 * 2]     : 0.f;
    const float wx01 = cv0 ? W_ih[nA0 * 2 + 1] : 0.f;
    const float bA0  = cv0 ? (b_ih[nA0] + b_hh[nA0]) : 0.f;
    const float wx10 = cv1 ? W_ih[nA1 * 2]     : 0.f;
    const float wx11 = cv1 ? W_ih[nA1 * 2 + 1] : 0.f;
    const float bA1  = cv1 ? (b_ih[nA1] + b_hh[nA1]) : 0.f;

    // --- head constants (drain path): lane covers cols 4*lane..+3 ---
    const int c4 = 4 * lane;
    f4v wo = {0.f, 0.f, 0.f, 0.f};
    if (c4 + 3 < H) wo = *(const f4v*)(W_out + c4);   // pads: wo = 0
    const float bo = b_out[0];

    __syncthreads();

    float* const op = out + b;
    const unsigned short* const aptr = &ring[0][(m == 1) ? 1 : 0][8 * q];

    // drain output td: 2 b64 reads + VALU-only 64-lane reduce -> obuf.
    auto drain = [&](int td) {
        const int slot = td & (RS - 1);
        float v = 0.f;
        if (lane < 56) {   // cols 0..223; pads are 0 and wo=0 there
            const s4v hv = *(const s4v*)(&ring[slot][0][0] + c4);
            const s4v lv = *(const s4v*)(&ring[slot][1][0] + c4);
            v = (h2f((unsigned short)hv[0]) + h2f((unsigned short)lv[0])) * wo[0]
              + (h2f((unsigned short)hv[1]) + h2f((unsigned short)lv[1])) * wo[1]
              + (h2f((unsigned short)hv[2]) + h2f((unsigned short)lv[2])) * wo[2]
              + (h2f((unsigned short)hv[3]) + h2f((unsigned short)lv[3])) * wo[3];
        }
        // xor-butterfly within 16 lanes: quad xor1, xor2, half-mirror,
        // mirror (all VALU DPP) -> every lane holds its row16 sum.
        v = dpp_add<0xB1>(v);    // quad_perm(1,0,3,2)
        v = dpp_add<0x4E>(v);    // quad_perm(2,3,0,1)
        v = dpp_add<0x141>(v);   // row_half_mirror
        v = dpp_add<0x140>(v);   // row_mirror
        const float r1 = __builtin_bit_cast(float,
            __builtin_amdgcn_readlane(__builtin_bit_cast(int, v), 16));
        const float r2 = __builtin_bit_cast(float,
            __builtin_amdgcn_readlane(__builtin_bit_cast(int, v), 32));
        const float r3 = __builtin_bit_cast(float,
            __builtin_amdgcn_readlane(__builtin_bit_cast(int, v), 48));
        if (lane == 0) obuf[td & 127] = ((v + r1) + (r2 + r3)) + bo;
    };

    // epilogue+write for one tile (q==0 lanes): DPP-paired b32 store.
    auto finish = [&](float y, float xterm, int nA, int sw) {
        const float pre = y + xterm;
        const float e   = __expf(2.f * pre);      // tanh, saturating
        const float th  = 1.f - 2.f / (e + 1.f);
        const unsigned short hi = f2h(th);
        const unsigned short lo = f2h(th - h2f(hi));
        const int nhi = __builtin_amdgcn_update_dpp(0, (int)hi, 0xB1, 0xF, 0xF, false);
        const int nlo = __builtin_amdgcn_update_dpp(0, (int)lo, 0xB1, 0xF, 0xF, false);
        const bool ev = ((m & 1) == 0);
        const unsigned int wd = ev
            ? ((unsigned)hi  | ((unsigned)nhi << 16))   // cols nA, nA+1 (hi)
            : ((unsigned)nlo | ((unsigned)lo  << 16));  // cols nA-1, nA (lo)
        unsigned short* wa = ev ? (&ring[sw][0][0] + nA)
                                : (&ring[sw][1][0] + nA - 1);
        *(unsigned int*)wa = wd;
    };

    for (int t = 0; t < T; ++t) {
        const int sr = (t + RS - 1) & (RS - 1);
        const int sw = t & (RS - 1);

        if (isTile) {
            const float2 xv = *(const float2*)(xs + 2 * t);
            const float xterm0 = fmaf(xv.x, wx00, fmaf(xv.y, wx01, bA0));
            const float xterm1 = fmaf(xv.x, wx10, fmaf(xv.y, wx11, bA1));

            // ONE A-read set (row0 h_hi, row1 h_lo) for both tiles.
            const unsigned short* ap = aptr + sr * 448;
            const s8v A0 = *(const s8v*)(ap);
            const s8v A1 = *(const s8v*)(ap + 32);
            const s8v A2 = *(const s8v*)(ap + 64);
            const s8v A3 = *(const s8v*)(ap + 96);
            const s8v A4 = *(const s8v*)(ap + 128);
            const s8v A5 = *(const s8v*)(ap + 160);
            const s8v A6 = *(const s8v*)(ap + 192);

            if (tn == 2) {
                f4v u0 = {0.f,0.f,0.f,0.f}, v0 = {0.f,0.f,0.f,0.f};
                f4v u1 = {0.f,0.f,0.f,0.f}, v1 = {0.f,0.f,0.f,0.f};
                u0 = __builtin_amdgcn_mfma_f32_16x16x32_f16(A0, BA0[0], u0, 0,0,0);
                u1 = __builtin_amdgcn_mfma_f32_16x16x32_f16(A0, BA1[0], u1, 0,0,0);
                v0 = __builtin_amdgcn_mfma_f32_16x16x32_f16(A4, BA0[4], v0, 0,0,0);
                v1 = __builtin_amdgcn_mfma_f32_16x16x32_f16(A4, BA1[4], v1, 0,0,0);
                u0 = __builtin_amdgcn_mfma_f32_16x16x32_f16(A1, BA0[1], u0, 0,0,0);
                u1 = __builtin_amdgcn_mfma_f32_16x16x32_f16(A1, BA1[1], u1, 0,0,0);
                v0 = __builtin_amdgcn_mfma_f32_16x16x32_f16(A5, BA0[5], v0, 0,0,0);
                v1 = __builtin_amdgcn_mfma_f32_16x16x32_f16(A5, BA1[5], v1, 0,0,0);
                u0 = __builtin_amdgcn_mfma_f32_16x16x32_f16(A2, BA0[2], u0, 0,0,0);
                u1 = __builtin_amdgcn_mfma_f32_16x16x32_f16(A2, BA1[2], u1, 0,0,0);
                v0 = __builtin_amdgcn_mfma_f32_16x16x32_f16(A6, BA0[6], v0, 0,0,0);
                v1 = __builtin_amdgcn_mfma_f32_16x16x32_f16(A6, BA1[6], v1, 0,0,0);
                u0 = __builtin_amdgcn_mfma_f32_16x16x32_f16(A3, BA0[3], u0, 0,0,0);
                u1 = __builtin_amdgcn_mfma_f32_16x16x32_f16(A3, BA1[3], u1, 0,0,0);
                if (q == 0) {
                    finish((u0[0]+u0[1]) + (v0[0]+v0[1]), xterm0, nA0, sw);
                    finish((u1[0]+u1[1]) + (v1[0]+v1[1]), xterm1, nA1, sw);
                }
            } else {
                f4v u = {0.f,0.f,0.f,0.f}, v = {0.f,0.f,0.f,0.f};
                u = __builtin_amdgcn_mfma_f32_16x16x32_f16(A0, BA0[0], u, 0,0,0);
                v = __builtin_amdgcn_mfma_f32_16x16x32_f16(A4, BA0[4], v, 0,0,0);
                u = __builtin_amdgcn_mfma_f32_16x16x32_f16(A1, BA0[1], u, 0,0,0);
                v = __builtin_amdgcn_mfma_f32_16x16x32_f16(A5, BA0[5], v, 0,0,0);
                u = __builtin_amdgcn_mfma_f32_16x16x32_f16(A2, BA0[2], u, 0,0,0);
                v = __builtin_amdgcn_mfma_f32_16x16x32_f16(A6, BA0[6], v, 0,0,0);
                u = __builtin_amdgcn_mfma_f32_16x16x32_f16(A3, BA0[3], u, 0,0,0);
                if (q == 0)
                    finish((u[0]+u[1]) + (v[0]+v[1]), xterm0, nA0, sw);
            }
        } else {
            // one drain per phase, 9 phases stale (slot td != sw, != sr).
            if (t >= 9 && w == 8 + ((t - 9) & 7)) drain(t - 9);
            // wave 14 is never the drain wave when (t&63)==16 -> flush.
            if (w == 14 && (t & 63) == 16 && t >= 80) {
                const int c = (t >> 6) - 1;                 // chunk 0..30
                const float val = obuf[((c & 1) << 6) | lane];
                op[(size_t)(64 * c + lane) * B] = val;
            }
        }
        __syncthreads();
    }

    // --- tail: outputs 2039..2047 not yet drained; then flush chunk 31 ---
    if (w >= 8) drain(2031 + w);       // 2039..2046
    if (w == 0) drain(2047);
    __syncthreads();
    if (w == 1) {
        const float val = obuf[64 | lane];   // outputs 1984..2047
        op[(size_t)(1984 + lane) * B] = val;
    }
}

extern "C" void kernel_launch(void* const* d_in, const int* in_sizes, int n_in,
                              void* d_out, int out_size, void* d_ws, size_t ws_size,
                              hipStream_t stream) {
    const float* x     = (const float*)d_in[0];
    const float* W_ih  = (const float*)d_in[1];
    const float* W_hh  = (const float*)d_in[2];
    const float* b_ih  = (const float*)d_in[3];
    const float* b_hh  = (const float*)d_in[4];
    const float* W_out = (const float*)d_in[5];
    const float* b_out = (const float*)d_in[6];
    float* out = (float*)d_out;

    rnn_fused<<<B, NTHR, 0, stream>>>(x, W_ih, W_hh, b_ih, b_hh, W_out, b_out, out);
}

// Round 7
// 1009.769 us; speedup vs baseline: 1.2800x; 1.1452x over previous
//
#include <hip/hip_runtime.h>
#include <hip/hip_fp16.h>

// RNN_16492674416646: h_t = tanh(x_t W_ih^T + b_ih + b_hh + h_{t-1} W_hh^T),
// out_t = h_t W_out^T + b_out. T=2048, B=128, IN=2, H=200, OUT=1, fp32.
//
// R19. Serial-path model (fits R13-R18b): step = longest wave's chain
// {barrier, ds_read latency, MFMA deps, epilogue VALU, write, barrier};
// read COUNT is off-path (R14/R17/R18b), per-wave MFMA count and epilogue
// are on-path (R15/R18b), stragglers poison (R16). R13 (7 MFMA, 1 finish,
// 4 w/SIMD) is the shortest path measured. R19 = R13 minus its remaining
// on-path items:
//  - drain phase REMOVED from tile waves (R13: every 9th step + extra
//    barrier). Aux waves 13/14 drain one output/step, 2 steps stale,
//    DPP-ONLY reduce (no shfl/LDS-pipe: R16's straggler bug; verified in
//    R18b). Wave 15 flushes 64 outputs to HBM once per 64 steps.
//  - x8 unroll: static ring slots (no slot VALU), xs as b128 per 4 steps.
//  - MFMA chains 2+2+2+1 (dep depth 4 -> 2).
// Numerics identical to R13 (fp16 W, split-fp16 h on A rows 0/1, same
// MFMA): absmax 0.0078 < 0.029. Ring slot stride 896 B == 0 mod 128 ->
// hi/lo bank-disjoint (lo at +448 B): conflict-free (R11-R18: 0).

typedef short s8v __attribute__((ext_vector_type(8)));   // 8 x fp16 bits
typedef short s4v __attribute__((ext_vector_type(4)));   // 4 x fp16 bits
typedef float f4v __attribute__((ext_vector_type(4)));

static constexpr int T = 2048;
static constexpr int B = 128;
static constexpr int H = 200;
static constexpr int NTHR = 1024;  // 16 waves
static constexpr int NT  = 13;     // n-tiles of 16 (208 >= 200)
static constexpr int KT  = 7;      // k-tiles of 32 (224 padded)
static constexpr int HP  = 224;    // padded H
static constexpr int RS  = 8;      // ring slots; T % RS == 0

__device__ __forceinline__ unsigned short f2h(float f) {
    const __half h = __float2half_rn(f);
    return *(const unsigned short*)&h;
}
__device__ __forceinline__ float h2f(unsigned short u) {
    const __half h = *(const __half*)&u;
    return __half2float(h);
}
// VALU-only cross-lane add (DPP); CTRL is a compile-time literal.
template <int CTRL>
__device__ __forceinline__ float dpp_add(float v) {
    const int i = __builtin_bit_cast(int, v);
    const int p = __builtin_amdgcn_update_dpp(0, i, CTRL, 0xF, 0xF, false);
    return v + __builtin_bit_cast(float, p);
}

__global__ __attribute__((amdgpu_flat_work_group_size(NTHR, NTHR),
                          amdgpu_waves_per_eu(4, 4)))
void rnn_fused(const float* __restrict__ x,     // [T,B,2]
               const float* __restrict__ W_ih,  // [H,2]
               const float* __restrict__ W_hh,  // [H,H]
               const float* __restrict__ b_ih,  // [H]
               const float* __restrict__ b_hh,  // [H]
               const float* __restrict__ W_out, // [1,H]
               const float* __restrict__ b_out, // [1]
               float* __restrict__ out)         // [T,B]
{
    const int b    = blockIdx.x;
    const int tid  = threadIdx.x;
    const int w    = tid >> 6;       // wave id 0..15
    const int lane = tid & 63;
    const int m    = lane & 15;      // A-row sel / B-col / D-col
    const int q    = lane >> 4;      // k-quad

    const bool hasT = (w < NT);      // 13 tile waves; 13/14 drain; 15 flush
    const int  nA   = 16 * w + m;
    const bool colv = hasT && (nA < H);

    __shared__ __align__(16) unsigned short ring[RS][2][HP];  // 7 KiB
    __shared__ __align__(16) float xs[2 * T];                 // 16 KiB
    __shared__ __align__(16) float obuf[128];                 // out staging

    for (int i = tid; i < RS * 2 * HP; i += NTHR) (&ring[0][0][0])[i] = 0;
    for (int idx = tid; idx < T; idx += NTHR) {
        const float2 v = *(const float2*)(x + (size_t)idx * (B * 2) + 2 * b);
        xs[2 * idx] = v.x; xs[2 * idx + 1] = v.y;
    }

    // --- loop-invariant B-fragment (fp16): B[k][n]=W_hh[n][k], n=nA ---
    s8v BA[KT];
#pragma unroll
    for (int kt = 0; kt < KT; ++kt) {
        s8v ba{};
        if (colv) {
#pragma unroll
            for (int j = 0; j < 8; ++j) {
                const int ks = 32 * kt + 8 * q + j;
                ba[j] = (short)((ks < H) ? f2h(W_hh[nA * H + ks])
                                         : (unsigned short)0);
            }
        }
        BA[kt] = ba;
    }

    // --- epilogue constants (q==0 lanes of tile waves own col nA) ---
    const float wxA0 = colv ? W_ih[nA * 2]     : 0.f;
    const float wxA1 = colv ? W_ih[nA * 2 + 1] : 0.f;
    const float bA   = colv ? (b_ih[nA] + b_hh[nA]) : 0.f;

    // --- head constants (drain path): lane covers cols 4*lane..+3 ---
    const int c4 = 4 * lane;
    f4v wo = {0.f, 0.f, 0.f, 0.f};
    if (c4 + 3 < H) wo = *(const f4v*)(W_out + c4);   // pads: wo = 0
    const float bo = b_out[0];

    __syncthreads();

    float* const op = out + b;
    const unsigned short* const aptr = &ring[0][(m == 1) ? 1 : 0][8 * q];

    // drain output tout (slot static): 2 b64 reads + DPP-only reduce.
    auto drain = [&](int slot, int tout) {
        float v = 0.f;
        if (lane < 56) {   // cols 0..223; pads are 0 and wo=0 there
            const s4v hv = *(const s4v*)(&ring[slot][0][0] + c4);
            const s4v lv = *(const s4v*)(&ring[slot][1][0] + c4);
            v = (h2f((unsigned short)hv[0]) + h2f((unsigned short)lv[0])) * wo[0]
              + (h2f((unsigned short)hv[1]) + h2f((unsigned short)lv[1])) * wo[1]
              + (h2f((unsigned short)hv[2]) + h2f((unsigned short)lv[2])) * wo[2]
              + (h2f((unsigned short)hv[3]) + h2f((unsigned short)lv[3])) * wo[3];
        }
        v = dpp_add<0xB1>(v);    // quad_perm(1,0,3,2)
        v = dpp_add<0x4E>(v);    // quad_perm(2,3,0,1)
        v = dpp_add<0x141>(v);   // row_half_mirror
        v = dpp_add<0x140>(v);   // row_mirror  -> each lane: its row16 sum
        const float r1 = __builtin_bit_cast(float,
            __builtin_amdgcn_readlane(__builtin_bit_cast(int, v), 16));
        const float r2 = __builtin_bit_cast(float,
            __builtin_amdgcn_readlane(__builtin_bit_cast(int, v), 32));
        const float r3 = __builtin_bit_cast(float,
            __builtin_amdgcn_readlane(__builtin_bit_cast(int, v), 48));
        if (lane == 0) obuf[tout & 127] = ((v + r1) + (r2 + r3)) + bo;
    };

    for (int t8 = 0; t8 < T / RS; ++t8) {
        f4v xv0 = {0.f, 0.f, 0.f, 0.f};
        f4v xv1 = {0.f, 0.f, 0.f, 0.f};
#pragma unroll
        for (int rp = 0; rp < RS; ++rp) {
            const int t  = 8 * t8 + rp;
            const int sr = (rp + RS - 1) & (RS - 1);   // static read slot

            if (hasT) {
                if (rp == 0) {          // x for steps rp=0..3
                    xv0 = *(const f4v*)(xs + 16 * t8);
                    xv1 = *(const f4v*)(xs + 16 * t8 + 4);
                } else if (rp == 4) {   // x for steps rp=4..7
                    xv0 = *(const f4v*)(xs + 16 * t8 + 8);
                    xv1 = *(const f4v*)(xs + 16 * t8 + 12);
                }
                const int r2i = rp & 3;  // static register picks
                const float x0 = (r2i == 0) ? xv0[0] : (r2i == 1) ? xv0[2]
                               : (r2i == 2) ? xv1[0] : xv1[2];
                const float x1 = (r2i == 0) ? xv0[1] : (r2i == 1) ? xv0[3]
                               : (r2i == 2) ? xv1[1] : xv1[3];
                const float xterm = fmaf(x0, wxA0, fmaf(x1, wxA1, bA));

                // A: row0 h_hi, row1 h_lo; vaddr invariant, slot static.
                const unsigned short* ap = aptr + sr * 448;
                const s8v A0 = *(const s8v*)(ap);
                const s8v A1 = *(const s8v*)(ap + 32);
                const s8v A2 = *(const s8v*)(ap + 64);
                const s8v A3 = *(const s8v*)(ap + 96);
                const s8v A4 = *(const s8v*)(ap + 128);
                const s8v A5 = *(const s8v*)(ap + 160);
                const s8v A6 = *(const s8v*)(ap + 192);

                // 4 chains, dep depth <= 2
                f4v u0 = {0.f, 0.f, 0.f, 0.f};
                f4v u1 = {0.f, 0.f, 0.f, 0.f};
                f4v u2 = {0.f, 0.f, 0.f, 0.f};
                f4v u3 = {0.f, 0.f, 0.f, 0.f};
                u0 = __builtin_amdgcn_mfma_f32_16x16x32_f16(A0, BA[0], u0, 0, 0, 0);
                u1 = __builtin_amdgcn_mfma_f32_16x16x32_f16(A2, BA[2], u1, 0, 0, 0);
                u2 = __builtin_amdgcn_mfma_f32_16x16x32_f16(A4, BA[4], u2, 0, 0, 0);
                u3 = __builtin_amdgcn_mfma_f32_16x16x32_f16(A6, BA[6], u3, 0, 0, 0);
                u0 = __builtin_amdgcn_mfma_f32_16x16x32_f16(A1, BA[1], u0, 0, 0, 0);
                u1 = __builtin_amdgcn_mfma_f32_16x16x32_f16(A3, BA[3], u1, 0, 0, 0);
                u2 = __builtin_amdgcn_mfma_f32_16x16x32_f16(A5, BA[5], u2, 0, 0, 0);

                if (q == 0 && nA < H) {
                    const float y = ((u0[0] + u0[1]) + (u1[0] + u1[1]))
                                  + ((u2[0] + u2[1]) + (u3[0] + u3[1]));
                    const float pre = y + xterm;
                    const float e   = __expf(2.f * pre);      // tanh
                    const float th  = 1.f - 2.f / (e + 1.f);
                    const unsigned short hi = f2h(th);
                    (&ring[rp][0][0])[nA] = hi;
                    (&ring[rp][1][0])[nA] = f2h(th - h2f(hi));
                }
            } else if (w == 13 + (rp & 1)) {
                // drain output t-2 (slot (rp+6)&7, static): written 2 steps
                // ago, rewritten at t+6 -> stable. w13: even t, w14: odd t.
                if (t8 > 0 || rp >= 2) drain((rp + 6) & (RS - 1), t - 2);
            } else if (w == 15) {
                // flush chunk cc = outputs [64cc, 64cc+64) once per 64
                // steps; last of chunk drained at step 64cc+65 <= t here.
                if (rp == 0 && (t8 & 7) == 2 && t8 >= 10) {
                    const int cc = (t8 - 10) >> 3;            // 0..30
                    const float val = obuf[((cc & 1) << 6) | lane];
                    op[(size_t)(64 * cc + lane) * B] = val;
                }
            }
            __syncthreads();
        }
    }

    // --- tail: outputs 2046,2047 undrained; then flush chunk 31 ---
    if (w == 13) drain(6, 2046);
    if (w == 14) drain(7, 2047);
    __syncthreads();
    if (w == 15) {
        const float val = obuf[64 | lane];   // outputs 1984..2047
        op[(size_t)(1984 + lane) * B] = val;
    }
}

extern "C" void kernel_launch(void* const* d_in, const int* in_sizes, int n_in,
                              void* d_out, int out_size, void* d_ws, size_t ws_size,
                              hipStream_t stream) {
    const float* x     = (const float*)d_in[0];
    const float* W_ih  = (const float*)d_in[1];
    const float* W_hh  = (const float*)d_in[2];
    const float* b_ih  = (const float*)d_in[3];
    const float* b_hh  = (const float*)d_in[4];
    const float* W_out = (const float*)d_in[5];
    const float* b_out = (const float*)d_in[6];
    float* out = (float*)d_out;

    rnn_fused<<<B, NTHR, 0, stream>>>(x, W_ih, W_hh, b_ih, b_hh, W_out, b_out, out);
}